// Round 4
// baseline (328.611 us; speedup 1.0000x reference)
//
#include <hip/hip_runtime.h>
#include <math.h>

// Problem constants
#define NTHETA  360
#define NLAMBDA 720
#define MMAX    361
#define NROWS   2880                       /* 8 heads * 360 theta rows */
#define ANGD (6.283185307179586476925286766559 / 720.0)  /* 2*pi/720 */

// DFT tiling (double-folded j: 181 terms padded to 192)
#define MT 128
#define RT 64
#define JCB 24
#define MPAD 384
#define JROWS2 192

// Workspace: Tc[192][384] | XF2[2880][384] | P[S][384][2880] | outT[361][8][360]
#define TC2_ELEMS  ((size_t)JROWS2 * MPAD)         /* 73,728 floats    */
#define XF_ELEMS   ((size_t)NROWS * MPAD)          /* 1,105,920 floats */
#define P_STRIDE   ((size_t)MPAD * NROWS)          /* 1,105,920 floats */
#define OUTT_ELEMS ((size_t)MMAX * 8 * NTHETA)     /* 1,039,680 floats */

// ---------------------------------------------------------------------------
// Prep: cos table (double-folded j) + quarter-fold of x over longitude.
// Exact identities (integer phases, Delta = 2*pi/720):
//   cos(D*(720-j)m) =  cos(D*j*m)          -> first fold  (j: 720 -> 361)
//   cos(D*(360-j)m) = (-1)^m cos(D*j*m)    -> second fold (j: 361 -> 181)
// XF2[row][par*192+j], j in [0,180]:
//   j=0:    e = x0+x360,              o = x0-x360
//   0<j<180: e = xj+x(720-j)+x(360-j)+x(360+j),  o = xj+x(720-j)-x(360-j)-x(360+j)
//   j=180:  e = x180+x540,            o = 0
// Re X[m] = sum_{j=0}^{180} Tc[j][m] * XF2[row][(m&1)*192+j]
// ---------------------------------------------------------------------------
__global__ __launch_bounds__(256) void prep_kernel(
    const float* __restrict__ x, float* __restrict__ Tc, float* __restrict__ XF2) {
    int i = blockIdx.x * 256 + threadIdx.x;
    if (i < (int)TC2_ELEMS) {
        int j = i / MPAD, mp = i % MPAD;
        float v = 0.f;
        if (j <= 180 && mp < MMAX) {
            int p = (j * mp) % 720;
            v = (float)ANGD * cosf((float)(ANGD * (double)p));
        }
        Tc[i] = v;
    } else {
        int t = i - (int)TC2_ELEMS;
        if (t < (int)XF_ELEMS) {
            int row = t / MPAD, col = t % MPAD;
            const float* xr = x + (size_t)row * 720;
            const int par = col / 192;            // 0 = even fold, 1 = odd fold
            const int j   = col % 192;
            float v = 0.f;
            if (j == 0) {
                v = par ? (xr[0] - xr[360]) : (xr[0] + xr[360]);
            } else if (j < 180) {
                float a = xr[j] + xr[720 - j];
                float b = xr[360 - j] + xr[360 + j];
                v = par ? (a - b) : (a + b);
            } else if (j == 180) {
                v = par ? 0.f : (xr[180] + xr[540]);
            }
            XF2[t] = v;
        }
    }
}

// ---------------------------------------------------------------------------
// Real DFT as register-tiled GEMM over double-folded j (192 padded terms).
// grid (3 mt, 45 rt, S jsplit), block 256. Per-thread 8m x 4r accumulator.
// Thread's 8 m-values are consecutive -> parity alternates with mi, so
// even accumulators consume the even-fold x, odd accumulators the odd-fold.
// ---------------------------------------------------------------------------
__global__ __launch_bounds__(256) void dft_re_kernel(
    const float* __restrict__ XF2, const float* __restrict__ Tc,
    float* __restrict__ P, int S) {
    const int mt  = blockIdx.x;
    const int rt  = blockIdx.y;
    const int s   = blockIdx.z;
    const int tid = threadIdx.x;
    const int tm  = tid & 15;
    const int tr  = tid >> 4;
    const int m0g = mt * MT;
    const int mo  = tm * 8;
    const int rb  = rt * RT;
    const int tr4 = tr * 4;
    const int jlen = JROWS2 / S;
    const int j0   = s * jlen;

    __shared__ __align__(16) float tc[JCB][MT + 4];
    __shared__ __align__(16) float xs[JCB][2][72];

    float acc[8][4];
#pragma unroll
    for (int a = 0; a < 8; ++a)
#pragma unroll
        for (int b = 0; b < 4; ++b) acc[a][b] = 0.f;

    for (int jc = 0; jc < jlen; jc += JCB) {
        __syncthreads();
        for (int i = tid; i < JCB * MT; i += 256) {
            int jj = i >> 7;
            int mm = i & (MT - 1);
            tc[jj][mm] = Tc[(size_t)(j0 + jc + jj) * MPAD + m0g + mm];
        }
        for (int i = tid; i < JCB * RT * 2; i += 256) {
            int jj = i % JCB;
            int pr = (i / JCB) & 1;
            int rr = i / (JCB * 2);
            xs[jj][pr][rr] = XF2[(size_t)(rb + rr) * MPAD + pr * 192 + j0 + jc + jj];
        }
        __syncthreads();

        for (int jb = 0; jb < JCB; jb += 4) {
#pragma unroll
            for (int u = 0; u < 4; ++u) {
                float4 ta = *(const float4*)&tc[jb + u][mo];
                float4 tb = *(const float4*)&tc[jb + u][mo + 4];
                float4 xE = *(const float4*)&xs[jb + u][0][tr4];
                float4 xO = *(const float4*)&xs[jb + u][1][tr4];
#pragma unroll
                for (int i = 0; i < 4; ++i) {
                    float e = (i == 0) ? xE.x : (i == 1) ? xE.y : (i == 2) ? xE.z : xE.w;
                    float o = (i == 0) ? xO.x : (i == 1) ? xO.y : (i == 2) ? xO.z : xO.w;
                    acc[0][i] += ta.x * e;
                    acc[1][i] += ta.y * o;
                    acc[2][i] += ta.z * e;
                    acc[3][i] += ta.w * o;
                    acc[4][i] += tb.x * e;
                    acc[5][i] += tb.y * o;
                    acc[6][i] += tb.z * e;
                    acc[7][i] += tb.w * o;
                }
            }
        }
    }

#pragma unroll
    for (int mi = 0; mi < 8; ++mi) {
        float* dst = P + ((size_t)s * MPAD + m0g + mo + mi) * NROWS + rb + tr4;
        *(float4*)dst = make_float4(acc[mi][0], acc[mi][1], acc[mi][2], acc[mi][3]);
    }
}

// ---------------------------------------------------------------------------
// Contraction with in-block j-split reduction + theta parity fold:
//   a = sum_s P[s][m][h*360+k],  b = sum_s P[s][m][h*360+359-k]   (k<180)
//   xef[h*180+k] = a+b  (even),  xef[1440+h*180+k] = a-b  (odd)
//   outT[m][h][n] = sum_{k<180} W[m][n][k] * xef[par*1440 + h*180+k]
// Same arithmetic order as the old reduce_fold (sum over s, then +-), so the
// result is bit-identical; the separate PF pass + buffer are eliminated.
// 1D grid, XCD-clustered: all 12 n-tiles of a given m share wgid%8 -> one
// XCD's L2 serves P[.][m] (46 KB across S=4 slices) for 11 of 12 blocks.
//   bid = r + 8*c,  c = (m/8)*12 + nt,  r = m%8.   grid = 8*552 (84 masked)
// ---------------------------------------------------------------------------
__global__ __launch_bounds__(128, 1) void contract_re_kernel(
    const float* __restrict__ W, const float* __restrict__ P,
    float* __restrict__ outT, int S) {
    const int bid = blockIdx.x;
    const int r   = bid & 7;
    const int c   = bid >> 3;
    const int nt  = c % 12;
    const int m   = (c / 12) * 8 + r;
    if (m > 360) return;
    const int tid = threadIdx.x;
    const int q   = tid & 7;             // k-phase
    const int np  = tid >> 3;            // 0..15

    __shared__ __align__(16) float xef[NROWS];           // 11.5 KB (even|odd)
    __shared__ float pl[16 * 2 * 8 * 8];                 // 8 KB partials

    for (int i = tid; i < 8 * 180; i += 128) {
        const int h = i / 180, k = i % 180;
        const size_t base = (size_t)m * NROWS + h * 360;
        float a = 0.f, b = 0.f;
        for (int s = 0; s < S; ++s) {
            const float* p = P + (size_t)s * P_STRIDE + base;
            a += p[k];
            b += p[359 - k];
        }
        xef[i]        = a + b;
        xef[1440 + i] = a - b;
    }
    __syncthreads();

    const int n0 = nt * 32;
    int na = n0 + np;      if (na > 359) na = 359;       // clamp (dup read, store masked)
    int nb = n0 + np + 16; if (nb > 359) nb = 359;
    const float4* wa = (const float4*)(W + ((size_t)m * 360 + na) * 360);
    const float4* wb = (const float4*)(W + ((size_t)m * 360 + nb) * 360);
    const int par = (m + n0 + np) & 1;                   // same parity for na, nb
    const float* xb = &xef[par * 1440];

    float acc[2][8];
#pragma unroll
    for (int j = 0; j < 2; ++j)
#pragma unroll
        for (int h = 0; h < 8; ++h) acc[j][h] = 0.f;

    float4 A0 = wa[q], B0 = wb[q];
    for (int s = 0; s < 6; ++s) {
        const int f4 = q + 8 * s;
        if (f4 >= 45) break;                              // 45 float4 = 180 k
        const int f4n = f4 + 8;
        float4 An = A0, Bn = B0;
        if (f4n < 45) { An = wa[f4n]; Bn = wb[f4n]; }     // prefetch next step

        float4 xv[8];
#pragma unroll
        for (int h = 0; h < 8; ++h)
            xv[h] = *(const float4*)&xb[h * 180 + f4 * 4];
#pragma unroll
        for (int h = 0; h < 8; ++h) {
            acc[0][h] += A0.x * xv[h].x + A0.y * xv[h].y + A0.z * xv[h].z + A0.w * xv[h].w;
            acc[1][h] += B0.x * xv[h].x + B0.y * xv[h].y + B0.z * xv[h].z + B0.w * xv[h].w;
        }
        A0 = An; B0 = Bn;
    }

    // partials: pl[((np*2+j)*8+h)*8+q]
#pragma unroll
    for (int j = 0; j < 2; ++j)
#pragma unroll
        for (int h = 0; h < 8; ++h)
            pl[((np * 2 + j) * 8 + h) * 8 + q] = acc[j][h];
    __syncthreads();

    // reduce over q and store: 256 outputs (32 n x 8 h), 2 per thread
    for (int oi = tid; oi < 256; oi += 128) {
        const int n_loc = oi >> 3;       // 0..31
        const int h     = oi & 7;
        const int npp   = n_loc & 15, j = n_loc >> 4;
        const float* p = &pl[((npp * 2 + j) * 8 + h) * 8];
        float sum = p[0] + p[1] + p[2] + p[3] + p[4] + p[5] + p[6] + p[7];
        const int n = n0 + n_loc;
        if (n < NTHETA)
            outT[((size_t)m * 8 + h) * 360 + n] = sum;
    }
}

// ---------------------------------------------------------------------------
// Transpose outT[m][h][n] -> out[h][n][m]
// ---------------------------------------------------------------------------
__global__ __launch_bounds__(256) void transpose_kernel(
    const float* __restrict__ outT, float* __restrict__ out, long long out_elems) {
    __shared__ float t[32][33];
    const int mt = blockIdx.x, nt = blockIdx.y, h = blockIdx.z;
    const int cx = threadIdx.x, cy = threadIdx.y;

#pragma unroll
    for (int ri = 0; ri < 4; ++ri) {
        int r = cy + ri * 8;
        int mm = mt * 32 + r, nn = nt * 32 + cx;
        float v = 0.f;
        if (mm < MMAX && nn < NTHETA)
            v = outT[((size_t)mm * 8 + h) * 360 + nn];
        t[r][cx] = v;
    }
    __syncthreads();
#pragma unroll
    for (int ri = 0; ri < 4; ++ri) {
        int r = cy + ri * 8;
        int nn = nt * 32 + r, mm = mt * 32 + cx;
        if (mm < MMAX && nn < NTHETA) {
            size_t oidx = ((size_t)(h * 360) + nn) * 361 + mm;
            if (oidx < (size_t)out_elems) out[oidx] = t[cx][r];
        }
    }
}

// ---------------------------------------------------------------------------
// Fallback: fused, exact integer-phase double trig (no folds — safe path).
// ---------------------------------------------------------------------------
__global__ __launch_bounds__(256) void fused_kernel(
    const float* __restrict__ x, const float* __restrict__ W,
    float* __restrict__ out, long long nx, long long nw, long long out_elems,
    int complexOut) {
    const int m   = blockIdx.x;
    const int tid = threadIdx.x;

    __shared__ float xl[16 * 360];

    for (int row = tid; row < NROWS; row += 256) {
        int h = row / 360, k = row % 360;
        const size_t base = (size_t)row * 720;
        float ar = 0.f, ai = 0.f;
        if (base + 720 <= (size_t)nx) {
            const float* xr = x + base;
            for (int j = 0; j < 720; ++j) {
                int p = (j * m) % 720;
                double a = ANGD * (double)p;
                float xe = xr[j];
                ar += xe * (float)(ANGD * cos(a));
                ai -= xe * (float)(ANGD * sin(a));
            }
        }
        xl[(h * 2) * 360 + k]     = ar;
        xl[(h * 2 + 1) * 360 + k] = ai;
    }
    __syncthreads();

    for (int n = tid; n < 360; n += 256) {
        float accr[8], acci[8];
#pragma unroll
        for (int i = 0; i < 8; ++i) { accr[i] = 0.f; acci[i] = 0.f; }
        const size_t wbase = ((size_t)m * 360 + n) * 360;
        if (wbase + 360 <= (size_t)nw) {
            const float* wr = W + wbase;
            for (int k = 0; k < 360; ++k) {
                float w = wr[k];
#pragma unroll
                for (int h = 0; h < 8; ++h) {
                    accr[h] += w * xl[(h * 2) * 360 + k];
                    acci[h] += w * xl[(h * 2 + 1) * 360 + k];
                }
            }
        }
#pragma unroll
        for (int h = 0; h < 8; ++h) {
            size_t e = ((size_t)(h * 360) + n) * 361 + m;
            if (complexOut) {
                if (2 * e + 1 < (size_t)out_elems) {
                    out[2 * e]     = accr[h];
                    out[2 * e + 1] = acci[h];
                }
            } else {
                if (e < (size_t)out_elems) out[e] = accr[h];
            }
        }
    }
}

extern "C" void kernel_launch(void* const* d_in, const int* in_sizes, int n_in,
                              void* d_out, int out_size, void* d_ws, size_t ws_size,
                              hipStream_t stream) {
    if (n_in < 2) return;
    const float* x = (const float*)d_in[0];   // [1,8,360,720] float32
    const float* W = (const float*)d_in[1];   // [361,360,360] float32
    float* out = (float*)d_out;               // float32[out_size]; expected = Re(result)

    const long long nx = in_sizes[0];
    const long long nw = in_sizes[1];
    const long long out_elems = (long long)out_size;
    const bool complexOut = (out_elems >= 2LL * 1039680LL);
    const bool sizesOk = (nx >= 2073600LL) && (nw >= 46785600LL);

    int S = 0;
    for (int c = 4; c >= 1; c >>= 1) {
        size_t need = (TC2_ELEMS + XF_ELEMS + (size_t)c * P_STRIDE + OUTT_ELEMS)
                      * sizeof(float);
        if (ws_size >= need) { S = c; break; }
    }

    if (!complexOut && sizesOk && S > 0 && d_ws != nullptr) {
        float* Tc  = (float*)d_ws;
        float* XFp = Tc + TC2_ELEMS;
        float* P   = XFp + XF_ELEMS;
        float* oT  = P + (size_t)S * P_STRIDE;
        const int prep_blocks = (int)((TC2_ELEMS + XF_ELEMS + 255) / 256);
        prep_kernel<<<prep_blocks, 256, 0, stream>>>(x, Tc, XFp);
        dft_re_kernel<<<dim3(3, 45, S), 256, 0, stream>>>(XFp, Tc, P, S);
        contract_re_kernel<<<8 * 552, 128, 0, stream>>>(W, P, oT, S);
        transpose_kernel<<<dim3(12, 12, 8), dim3(32, 8), 0, stream>>>(oT, out, out_elems);
    } else {
        fused_kernel<<<dim3(361), 256, 0, stream>>>(x, W, out, nx, nw, out_elems,
                                                    complexOut ? 1 : 0);
    }
}

// Round 5
// 285.420 us; speedup vs baseline: 1.1513x; 1.1513x over previous
//
#include <hip/hip_runtime.h>
#include <math.h>

// Problem constants
#define NTHETA  360
#define NLAMBDA 720
#define MMAX    361
#define NROWS   2880                       /* 8 heads * 360 theta rows */
#define ANGD (6.283185307179586476925286766559 / 720.0)  /* 2*pi/720 */

// DFT tiling (double-folded j: 181 terms padded to 192)
#define MT 128
#define RT 64
#define JCB 24
#define MPAD 384
#define JROWS2 192

// Workspace: Tc[192][384] | XF2[2880][384] | P[S][384][2880] | PF[361][2880] | outT[361][8][360]
#define TC2_ELEMS  ((size_t)JROWS2 * MPAD)         /* 73,728 floats    */
#define XF_ELEMS   ((size_t)NROWS * MPAD)          /* 1,105,920 floats */
#define P_STRIDE   ((size_t)MPAD * NROWS)          /* 1,105,920 floats */
#define PF_ELEMS   ((size_t)MMAX * NROWS)          /* 1,039,680 floats */
#define OUTT_ELEMS ((size_t)MMAX * 8 * NTHETA)     /* 1,039,680 floats */

// ---------------------------------------------------------------------------
// Prep: cos table (double-folded j) + quarter-fold of x over longitude.
// Exact identities (integer phases, Delta = 2*pi/720):
//   cos(D*(720-j)m) =  cos(D*j*m)          -> first fold  (j: 720 -> 361)
//   cos(D*(360-j)m) = (-1)^m cos(D*j*m)    -> second fold (j: 361 -> 181)
// XF2[row][par*192+j], j in [0,180]:
//   j=0:    e = x0+x360,              o = x0-x360
//   0<j<180: e = xj+x(720-j)+x(360-j)+x(360+j),  o = xj+x(720-j)-x(360-j)-x(360+j)
//   j=180:  e = x180+x540,            o = 0
// Re X[m] = sum_{j=0}^{180} Tc[j][m] * XF2[row][(m&1)*192+j]
// ---------------------------------------------------------------------------
__global__ __launch_bounds__(256) void prep_kernel(
    const float* __restrict__ x, float* __restrict__ Tc, float* __restrict__ XF2) {
    int i = blockIdx.x * 256 + threadIdx.x;
    if (i < (int)TC2_ELEMS) {
        int j = i / MPAD, mp = i % MPAD;
        float v = 0.f;
        if (j <= 180 && mp < MMAX) {
            int p = (j * mp) % 720;
            v = (float)ANGD * cosf((float)(ANGD * (double)p));
        }
        Tc[i] = v;
    } else {
        int t = i - (int)TC2_ELEMS;
        if (t < (int)XF_ELEMS) {
            int row = t / MPAD, col = t % MPAD;
            const float* xr = x + (size_t)row * 720;
            const int par = col / 192;            // 0 = even fold, 1 = odd fold
            const int j   = col % 192;
            float v = 0.f;
            if (j == 0) {
                v = par ? (xr[0] - xr[360]) : (xr[0] + xr[360]);
            } else if (j < 180) {
                float a = xr[j] + xr[720 - j];
                float b = xr[360 - j] + xr[360 + j];
                v = par ? (a - b) : (a + b);
            } else if (j == 180) {
                v = par ? 0.f : (xr[180] + xr[540]);
            }
            XF2[t] = v;
        }
    }
}

// ---------------------------------------------------------------------------
// Real DFT as register-tiled GEMM over double-folded j (192 padded terms).
// grid (3 mt, 45 rt, S jsplit), block 256. Per-thread 8m x 4r accumulator.
// Thread's 8 m-values are consecutive -> parity alternates with mi, so
// even accumulators consume the even-fold x, odd accumulators the odd-fold.
// ---------------------------------------------------------------------------
__global__ __launch_bounds__(256) void dft_re_kernel(
    const float* __restrict__ XF2, const float* __restrict__ Tc,
    float* __restrict__ P, int S) {
    const int mt  = blockIdx.x;
    const int rt  = blockIdx.y;
    const int s   = blockIdx.z;
    const int tid = threadIdx.x;
    const int tm  = tid & 15;
    const int tr  = tid >> 4;
    const int m0g = mt * MT;
    const int mo  = tm * 8;
    const int rb  = rt * RT;
    const int tr4 = tr * 4;
    const int jlen = JROWS2 / S;
    const int j0   = s * jlen;

    __shared__ __align__(16) float tc[JCB][MT + 4];
    __shared__ __align__(16) float xs[JCB][2][72];

    float acc[8][4];
#pragma unroll
    for (int a = 0; a < 8; ++a)
#pragma unroll
        for (int b = 0; b < 4; ++b) acc[a][b] = 0.f;

    for (int jc = 0; jc < jlen; jc += JCB) {
        __syncthreads();
        for (int i = tid; i < JCB * MT; i += 256) {
            int jj = i >> 7;
            int mm = i & (MT - 1);
            tc[jj][mm] = Tc[(size_t)(j0 + jc + jj) * MPAD + m0g + mm];
        }
        for (int i = tid; i < JCB * RT * 2; i += 256) {
            int jj = i % JCB;
            int pr = (i / JCB) & 1;
            int rr = i / (JCB * 2);
            xs[jj][pr][rr] = XF2[(size_t)(rb + rr) * MPAD + pr * 192 + j0 + jc + jj];
        }
        __syncthreads();

        for (int jb = 0; jb < JCB; jb += 4) {
#pragma unroll
            for (int u = 0; u < 4; ++u) {
                float4 ta = *(const float4*)&tc[jb + u][mo];
                float4 tb = *(const float4*)&tc[jb + u][mo + 4];
                float4 xE = *(const float4*)&xs[jb + u][0][tr4];
                float4 xO = *(const float4*)&xs[jb + u][1][tr4];
#pragma unroll
                for (int i = 0; i < 4; ++i) {
                    float e = (i == 0) ? xE.x : (i == 1) ? xE.y : (i == 2) ? xE.z : xE.w;
                    float o = (i == 0) ? xO.x : (i == 1) ? xO.y : (i == 2) ? xO.z : xO.w;
                    acc[0][i] += ta.x * e;
                    acc[1][i] += ta.y * o;
                    acc[2][i] += ta.z * e;
                    acc[3][i] += ta.w * o;
                    acc[4][i] += tb.x * e;
                    acc[5][i] += tb.y * o;
                    acc[6][i] += tb.z * e;
                    acc[7][i] += tb.w * o;
                }
            }
        }
    }

#pragma unroll
    for (int mi = 0; mi < 8; ++mi) {
        float* dst = P + ((size_t)s * MPAD + m0g + mo + mi) * NROWS + rb + tr4;
        *(float4*)dst = make_float4(acc[mi][0], acc[mi][1], acc[mi][2], acc[mi][3]);
    }
}

// ---------------------------------------------------------------------------
// Sum j-split partials AND apply the exact theta parity fold, float4 both
// directions (reversed load + component swap for the mirrored half):
//   a[i] = sum_s P[s][m][h*360+4k4+i],  b[i] = sum_s P[s][m][h*360+359-4k4-i]
//   PF[m][      h*180+4k4+i] = a[i]+b[i]   (even fold)
//   PF[m][1440+ h*180+4k4+i] = a[i]-b[i]   (odd fold)
// Per-element arithmetic order identical to the scalar version -> bit-identical.
// ---------------------------------------------------------------------------
__global__ __launch_bounds__(256) void reduce_fold_kernel(
    const float* __restrict__ P, float* __restrict__ PF, int S) {
    int t = blockIdx.x * 256 + threadIdx.x;   // (m*8+h)*45 + k4
    if (t >= MMAX * 8 * 45) return;
    const int k4 = t % 45;
    const int mh = t / 45;
    const int h  = mh & 7;
    const int m  = mh >> 3;
    const size_t base = (size_t)m * NROWS + h * 360;
    float4 a = make_float4(0.f, 0.f, 0.f, 0.f);
    float4 b = make_float4(0.f, 0.f, 0.f, 0.f);
    for (int s = 0; s < S; ++s) {
        const float* p = P + (size_t)s * P_STRIDE + base;
        float4 va = *(const float4*)&p[k4 * 4];
        float4 vb = *(const float4*)&p[356 - k4 * 4];
        a.x += va.x; a.y += va.y; a.z += va.z; a.w += va.w;
        b.x += vb.w; b.y += vb.z; b.z += vb.y; b.w += vb.x;   // b[i] = p[359-4k4-i]
    }
    float* dst = PF + (size_t)m * NROWS + h * 180 + k4 * 4;
    *(float4*)dst          = make_float4(a.x + b.x, a.y + b.y, a.z + b.z, a.w + b.w);
    *(float4*)(dst + 1440) = make_float4(a.x - b.x, a.y - b.y, a.z - b.z, a.w - b.w);
}

// ---------------------------------------------------------------------------
// Contraction over pre-folded latitudes:
//   outT[m][h][n] = sum_{k<180} W[m][n][k] * PF[m][par][h][k],  par=(m+n)&1
// 1D grid, XCD-clustered: all 12 n-tiles of a given m share wgid%8, so they
// land on one XCD and PF[m] (11.5 KB) is fetched into exactly one L2.
//   bid = r + 8*c,  c = (m/8)*12 + nt,  r = m%8.   grid = 8*552 (84 masked)
// ---------------------------------------------------------------------------
__global__ __launch_bounds__(128, 1) void contract_re_kernel(
    const float* __restrict__ W, const float* __restrict__ PF,
    float* __restrict__ outT) {
    const int bid = blockIdx.x;
    const int r   = bid & 7;
    const int c   = bid >> 3;
    const int nt  = c % 12;
    const int m   = (c / 12) * 8 + r;
    if (m > 360) return;
    const int tid = threadIdx.x;
    const int q   = tid & 7;             // k-phase
    const int np  = tid >> 3;            // 0..15

    __shared__ __align__(16) float xef[NROWS];           // 11.5 KB (even|odd)
    __shared__ float pl[16 * 2 * 8 * 8];                 // 8 KB partials

    const float4* src = (const float4*)(PF + (size_t)m * NROWS);
    for (int i = tid; i < NROWS / 4; i += 128)
        ((float4*)xef)[i] = src[i];
    __syncthreads();

    const int n0 = nt * 32;
    int na = n0 + np;      if (na > 359) na = 359;       // clamp (dup read, store masked)
    int nb = n0 + np + 16; if (nb > 359) nb = 359;
    const float4* wa = (const float4*)(W + ((size_t)m * 360 + na) * 360);
    const float4* wb = (const float4*)(W + ((size_t)m * 360 + nb) * 360);
    const int par = (m + n0 + np) & 1;                   // same parity for na, nb
    const float* xb = &xef[par * 1440];

    float acc[2][8];
#pragma unroll
    for (int j = 0; j < 2; ++j)
#pragma unroll
        for (int h = 0; h < 8; ++h) acc[j][h] = 0.f;

    float4 A0 = wa[q], B0 = wb[q];
    for (int s = 0; s < 6; ++s) {
        const int f4 = q + 8 * s;
        if (f4 >= 45) break;                              // 45 float4 = 180 k
        const int f4n = f4 + 8;
        float4 An = A0, Bn = B0;
        if (f4n < 45) { An = wa[f4n]; Bn = wb[f4n]; }     // prefetch next step

        float4 xv[8];
#pragma unroll
        for (int h = 0; h < 8; ++h)
            xv[h] = *(const float4*)&xb[h * 180 + f4 * 4];
#pragma unroll
        for (int h = 0; h < 8; ++h) {
            acc[0][h] += A0.x * xv[h].x + A0.y * xv[h].y + A0.z * xv[h].z + A0.w * xv[h].w;
            acc[1][h] += B0.x * xv[h].x + B0.y * xv[h].y + B0.z * xv[h].z + B0.w * xv[h].w;
        }
        A0 = An; B0 = Bn;
    }

    // partials: pl[((np*2+j)*8+h)*8+q]
#pragma unroll
    for (int j = 0; j < 2; ++j)
#pragma unroll
        for (int h = 0; h < 8; ++h)
            pl[((np * 2 + j) * 8 + h) * 8 + q] = acc[j][h];
    __syncthreads();

    // reduce over q and store: 256 outputs (32 n x 8 h), 2 per thread
    for (int oi = tid; oi < 256; oi += 128) {
        const int n_loc = oi >> 3;       // 0..31
        const int h     = oi & 7;
        const int npp   = n_loc & 15, j = n_loc >> 4;
        const float* p = &pl[((npp * 2 + j) * 8 + h) * 8];
        float sum = p[0] + p[1] + p[2] + p[3] + p[4] + p[5] + p[6] + p[7];
        const int n = n0 + n_loc;
        if (n < NTHETA)
            outT[((size_t)m * 8 + h) * 360 + n] = sum;
    }
}

// ---------------------------------------------------------------------------
// Transpose outT[m][h][n] -> out[h][n][m]
// ---------------------------------------------------------------------------
__global__ __launch_bounds__(256) void transpose_kernel(
    const float* __restrict__ outT, float* __restrict__ out, long long out_elems) {
    __shared__ float t[32][33];
    const int mt = blockIdx.x, nt = blockIdx.y, h = blockIdx.z;
    const int cx = threadIdx.x, cy = threadIdx.y;

#pragma unroll
    for (int ri = 0; ri < 4; ++ri) {
        int r = cy + ri * 8;
        int mm = mt * 32 + r, nn = nt * 32 + cx;
        float v = 0.f;
        if (mm < MMAX && nn < NTHETA)
            v = outT[((size_t)mm * 8 + h) * 360 + nn];
        t[r][cx] = v;
    }
    __syncthreads();
#pragma unroll
    for (int ri = 0; ri < 4; ++ri) {
        int r = cy + ri * 8;
        int nn = nt * 32 + r, mm = mt * 32 + cx;
        if (mm < MMAX && nn < NTHETA) {
            size_t oidx = ((size_t)(h * 360) + nn) * 361 + mm;
            if (oidx < (size_t)out_elems) out[oidx] = t[cx][r];
        }
    }
}

// ---------------------------------------------------------------------------
// Fallback: fused, exact integer-phase double trig (no folds — safe path).
// ---------------------------------------------------------------------------
__global__ __launch_bounds__(256) void fused_kernel(
    const float* __restrict__ x, const float* __restrict__ W,
    float* __restrict__ out, long long nx, long long nw, long long out_elems,
    int complexOut) {
    const int m   = blockIdx.x;
    const int tid = threadIdx.x;

    __shared__ float xl[16 * 360];

    for (int row = tid; row < NROWS; row += 256) {
        int h = row / 360, k = row % 360;
        const size_t base = (size_t)row * 720;
        float ar = 0.f, ai = 0.f;
        if (base + 720 <= (size_t)nx) {
            const float* xr = x + base;
            for (int j = 0; j < 720; ++j) {
                int p = (j * m) % 720;
                double a = ANGD * (double)p;
                float xe = xr[j];
                ar += xe * (float)(ANGD * cos(a));
                ai -= xe * (float)(ANGD * sin(a));
            }
        }
        xl[(h * 2) * 360 + k]     = ar;
        xl[(h * 2 + 1) * 360 + k] = ai;
    }
    __syncthreads();

    for (int n = tid; n < 360; n += 256) {
        float accr[8], acci[8];
#pragma unroll
        for (int i = 0; i < 8; ++i) { accr[i] = 0.f; acci[i] = 0.f; }
        const size_t wbase = ((size_t)m * 360 + n) * 360;
        if (wbase + 360 <= (size_t)nw) {
            const float* wr = W + wbase;
            for (int k = 0; k < 360; ++k) {
                float w = wr[k];
#pragma unroll
                for (int h = 0; h < 8; ++h) {
                    accr[h] += w * xl[(h * 2) * 360 + k];
                    acci[h] += w * xl[(h * 2 + 1) * 360 + k];
                }
            }
        }
#pragma unroll
        for (int h = 0; h < 8; ++h) {
            size_t e = ((size_t)(h * 360) + n) * 361 + m;
            if (complexOut) {
                if (2 * e + 1 < (size_t)out_elems) {
                    out[2 * e]     = accr[h];
                    out[2 * e + 1] = acci[h];
                }
            } else {
                if (e < (size_t)out_elems) out[e] = accr[h];
            }
        }
    }
}

extern "C" void kernel_launch(void* const* d_in, const int* in_sizes, int n_in,
                              void* d_out, int out_size, void* d_ws, size_t ws_size,
                              hipStream_t stream) {
    if (n_in < 2) return;
    const float* x = (const float*)d_in[0];   // [1,8,360,720] float32
    const float* W = (const float*)d_in[1];   // [361,360,360] float32
    float* out = (float*)d_out;               // float32[out_size]; expected = Re(result)

    const long long nx = in_sizes[0];
    const long long nw = in_sizes[1];
    const long long out_elems = (long long)out_size;
    const bool complexOut = (out_elems >= 2LL * 1039680LL);
    const bool sizesOk = (nx >= 2073600LL) && (nw >= 46785600LL);

    int S = 0;
    for (int c = 4; c >= 1; c >>= 1) {
        size_t need = (TC2_ELEMS + XF_ELEMS + (size_t)c * P_STRIDE + PF_ELEMS + OUTT_ELEMS)
                      * sizeof(float);
        if (ws_size >= need) { S = c; break; }
    }

    if (!complexOut && sizesOk && S > 0 && d_ws != nullptr) {
        float* Tc  = (float*)d_ws;
        float* XFp = Tc + TC2_ELEMS;
        float* P   = XFp + XF_ELEMS;
        float* PFp = P + (size_t)S * P_STRIDE;
        float* oT  = PFp + PF_ELEMS;
        const int prep_blocks = (int)((TC2_ELEMS + XF_ELEMS + 255) / 256);
        prep_kernel<<<prep_blocks, 256, 0, stream>>>(x, Tc, XFp);
        dft_re_kernel<<<dim3(3, 45, S), 256, 0, stream>>>(XFp, Tc, P, S);
        reduce_fold_kernel<<<(MMAX * 8 * 45 + 255) / 256, 256, 0, stream>>>(P, PFp, S);
        contract_re_kernel<<<8 * 552, 128, 0, stream>>>(W, PFp, oT);
        transpose_kernel<<<dim3(12, 12, 8), dim3(32, 8), 0, stream>>>(oT, out, out_elems);
    } else {
        fused_kernel<<<dim3(361), 256, 0, stream>>>(x, W, out, nx, nw, out_elems,
                                                    complexOut ? 1 : 0);
    }
}